// Round 5
// baseline (3061.249 us; speedup 1.0000x reference)
//
#include <hip/hip_runtime.h>

namespace {
constexpr int kB = 512;
constexpr int kT = 200;
constexpr int kI = 784;
constexpr int kH = 128;
constexpr int kO = 10;
constexpr int kM = kB * kT;  // 102400 rows
constexpr float kBeta = 0.9f;
constexpr float kThr = 1.0f;
}  // namespace

// Async global->LDS, 16 bytes per lane. LDS dest = wave-uniform base +
// lane*16; global source is per-lane. Size must be a literal.
__device__ __forceinline__ void gload_lds16(const float* g, float* l) {
  __builtin_amdgcn_global_load_lds(
      (const __attribute__((address_space(1))) float*)g,
      (__attribute__((address_space(3))) float*)l, 16, 0, 0);
}

// ---------------------------------------------------------------------------
// C[M][128] = A[M][K] . B[128][K]^T + bias.   K%16==0, M%128==0.
// 128x128 tile, BK=16, 256 threads, 8x8 per-thread register tile.
//
// Staging: global_load_lds width-16 (zero staging VGPRs, coalesced: each
// 64-lane chunk covers 16 rows x 64B, lanes permuted only WITHIN a 64B line).
// LDS layout (per matrix, 2048 dwords): slot(m,kk) =
//   (m>>1)*32 + ((((m&1)<<2)|(kk>>2)) ^ swz(m))*4 + (kk&3),
//   swz(m) = ((m>>1) ^ (m>>4)) & 7.
// DMA writes it linearly; the global source address is pre-swizzled (m201
// both-sides rule). Read addr = ibase(m) ^ (g<<4): A-reads conflict-free,
// B-reads 2-way (free).  Double-buffered LDS, ONE barrier per K-step,
// STAGE(s+1) issued before compute(s) (drain covered by 2048cy FMA).
// Nothing lives across a barrier except acc (AGPR-able) -> no spills
// (rounds 2-4 lesson: long-lived staging regs / 27 offset ints spilled GBs).
// ---------------------------------------------------------------------------
template <int K>
__global__ __launch_bounds__(256, 2) void gemm_nt128(
    const float* __restrict__ A, const float* __restrict__ B,
    const float* __restrict__ bias, float* __restrict__ C) {
  constexpr int BM = 128, BK = 16;
  constexpr int NSTEP = K / BK;
  __shared__ float As[2][2048];
  __shared__ float Bs[2][2048];
  const int tid = threadIdx.x;
  const int w = tid >> 6;       // wave 0..3
  const int lane = tid & 63;
  const int tx = tid & 15;      // n-dim
  const int ty = tid >> 4;      // m-dim 0..15
  const int row0 = blockIdx.x * BM;

  // Read-address byte bases into an 8KB LDS matrix buffer.
  int ibA[8], ibB[8];
#pragma unroll
  for (int i = 0; i < 8; ++i) {
    const int mA = (i < 4) ? (ty * 4 + i) : (64 + ty * 4 + (i - 4));
    const int sA = ((mA >> 1) ^ (mA >> 4)) & 7;
    ibA[i] = (mA >> 1) * 128 + ((((mA & 1) << 2) ^ sA) << 4);
    const int mB = (i < 4) ? (tx * 4 + i) : (64 + tx * 4 + (i - 4));
    const int sB = ((mB >> 1) ^ (mB >> 4)) & 7;
    ibB[i] = (mB >> 1) * 128 + ((((mB & 1) << 2) ^ sB) << 4);
  }

  // Staging decode: 8 chunks of 256 dwords per matrix; wave w owns chunks
  // w*2, w*2+1. Lane l of chunk c holds (m, kkgrp) st. its 16B lands at
  // LDS dwords c*256 + l*4 (linear), matching slot() above.
  int gsA[2], gsB[2], ldst[2];
#pragma unroll
  for (int t = 0; t < 2; ++t) {
    const int c = w * 2 + t;
    const int R = c * 8 + (lane >> 3);
    const int swz = (R ^ (R >> 3)) & 7;
    const int u = (lane & 7) ^ swz;
    const int m = 2 * R + (u >> 2);
    const int kg = u & 3;
    gsA[t] = (row0 + m) * K + kg * 4;
    gsB[t] = m * K + kg * 4;
    ldst[t] = c * 256;
  }

  auto STAGE = [&](int nxt, int k0) {
    float* ab = As[nxt];
    float* bb = Bs[nxt];
#pragma unroll
    for (int t = 0; t < 2; ++t) {
      gload_lds16(A + gsA[t] + k0, ab + ldst[t]);
      gload_lds16(B + gsB[t] + k0, bb + ldst[t]);
    }
  };

  float acc[8][8];
#pragma unroll
  for (int i = 0; i < 8; ++i)
#pragma unroll
    for (int j = 0; j < 8; ++j) acc[i][j] = 0.0f;

  STAGE(0, 0);
  __syncthreads();

  for (int s = 0; s < NSTEP; ++s) {
    const int cur = s & 1;
    if (s + 1 < NSTEP) STAGE(cur ^ 1, (s + 1) * BK);  // async, in flight
    const char* Ab = reinterpret_cast<const char*>(As[cur]);
    const char* Bb = reinterpret_cast<const char*>(Bs[cur]);
#pragma unroll
    for (int g = 0; g < 4; ++g) {      // kk group = kk/4
      float4 bf[8];
#pragma unroll
      for (int j = 0; j < 8; ++j)
        bf[j] = *reinterpret_cast<const float4*>(Bb + (ibB[j] ^ (g << 4)));
#pragma unroll
      for (int i = 0; i < 8; ++i) {
        const float4 af =
            *reinterpret_cast<const float4*>(Ab + (ibA[i] ^ (g << 4)));
#pragma unroll
        for (int j = 0; j < 8; ++j) {
          acc[i][j] = fmaf(af.x, bf[j].x, acc[i][j]);
          acc[i][j] = fmaf(af.y, bf[j].y, acc[i][j]);
          acc[i][j] = fmaf(af.z, bf[j].z, acc[i][j]);
          acc[i][j] = fmaf(af.w, bf[j].w, acc[i][j]);
        }
      }
    }
    if (s + 1 < NSTEP) __syncthreads();  // drains stage(s+1); frees buf cur
  }

#pragma unroll
  for (int i = 0; i < 8; ++i) {
    const int m = (i < 4) ? (ty * 4 + i) : (64 + ty * 4 + (i - 4));
    const size_t r = (size_t)(row0 + m);
#pragma unroll
    for (int jh = 0; jh < 2; ++jh) {
      const int n = jh * 64 + tx * 4;
      float4 v;
      v.x = acc[i][jh * 4 + 0] + bias[n + 0];
      v.y = acc[i][jh * 4 + 1] + bias[n + 1];
      v.z = acc[i][jh * 4 + 2] + bias[n + 2];
      v.w = acc[i][jh * 4 + 3] + bias[n + 3];
      *reinterpret_cast<float4*>(&C[r * 128 + n]) = v;
    }
  }
}

// ---------------------------------------------------------------------------
// In-place LIF scan over time for a [B,T,128] current buffer.
// thread = (b,h). m_new = (beta*m + cur) - s_prev ; s = (m_new > thr).
// Explicit _rn intrinsics forbid FMA contraction so the recurrence matches
// numpy's op-by-op rounding exactly.
// ---------------------------------------------------------------------------
__global__ __launch_bounds__(256) void lif_scan(float* __restrict__ buf) {
  const int g = blockIdx.x * 256 + threadIdx.x;  // 0..65535
  const int b = g >> 7;
  const int h = g & 127;
  const size_t base = (size_t)b * kT * 128 + h;
  float m = 0.0f, s = 0.0f;
#pragma unroll 4
  for (int t = 0; t < kT; ++t) {
    const float cur = buf[base + (size_t)t * 128];
    m = __fsub_rn(__fadd_rn(__fmul_rn(kBeta, m), cur), s);
    s = (m > kThr) ? 1.0f : 0.0f;
    buf[base + (size_t)t * 128] = s;
  }
}

// ---------------------------------------------------------------------------
// GEMM3: cur3[M][10] = s2[M][128] . W3[10][128]^T + b3. 64 rows / block,
// 320 threads, A-tile + W3 staged in LDS, 2 outputs per thread.
// ---------------------------------------------------------------------------
__global__ __launch_bounds__(320) void gemm3_n10(
    const float* __restrict__ A, const float* __restrict__ W3,
    const float* __restrict__ b3, float* __restrict__ C) {
  __shared__ float Ss[64][132];
  __shared__ float Ws[10][132];
  __shared__ float bs[10];
  const int tid = threadIdx.x;
  const size_t row0 = (size_t)blockIdx.x * 64;

  {  // stage W3: 10*128 floats = 320 float4, exactly one per thread
    const int r = tid >> 5;
    const int c4 = (tid & 31) * 4;
    const float4 v = *reinterpret_cast<const float4*>(&W3[r * 128 + c4]);
    Ws[r][c4 + 0] = v.x;
    Ws[r][c4 + 1] = v.y;
    Ws[r][c4 + 2] = v.z;
    Ws[r][c4 + 3] = v.w;
    if (tid < 10) bs[tid] = b3[tid];
  }
  for (int fi = tid; fi < 2048; fi += 320) {  // 64 rows * 32 float4
    const int r = fi >> 5;
    const int c4 = (fi & 31) * 4;
    const float4 v =
        *reinterpret_cast<const float4*>(&A[(row0 + r) * 128 + c4]);
    Ss[r][c4 + 0] = v.x;
    Ss[r][c4 + 1] = v.y;
    Ss[r][c4 + 2] = v.z;
    Ss[r][c4 + 3] = v.w;
  }
  __syncthreads();

#pragma unroll
  for (int l = 0; l < 2; ++l) {
    const int idx = tid + l * 320;  // 0..639
    const int r = idx / 10;
    const int o = idx - r * 10;
    float acc = bs[o];
#pragma unroll
    for (int k = 0; k < 128; k += 4) {
      const float4 a = *reinterpret_cast<const float4*>(&Ss[r][k]);
      const float4 w = *reinterpret_cast<const float4*>(&Ws[o][k]);
      acc = fmaf(a.x, w.x, acc);
      acc = fmaf(a.y, w.y, acc);
      acc = fmaf(a.z, w.z, acc);
      acc = fmaf(a.w, w.w, acc);
    }
    C[(row0 + r) * 10 + o] = acc;
  }
}

// ---------------------------------------------------------------------------
// Output LIF scan: thread = (b,o), reads cur3[(b*T+t)*10+o],
// writes spikes to out[t*B*10 + b*10 + o]  (layout [T,B,O]).
// ---------------------------------------------------------------------------
__global__ __launch_bounds__(256) void lif_scan_out(
    const float* __restrict__ cur3, float* __restrict__ out) {
  const int g = blockIdx.x * 256 + threadIdx.x;  // 0..5119
  if (g >= kB * kO) return;
  const int b = g / kO;
  const int o = g - b * kO;
  float m = 0.0f, s = 0.0f;
#pragma unroll 4
  for (int t = 0; t < kT; ++t) {
    const float c = cur3[((size_t)b * kT + t) * kO + o];
    m = __fsub_rn(__fadd_rn(__fmul_rn(kBeta, m), c), s);
    s = (m > kThr) ? 1.0f : 0.0f;
    out[(size_t)t * (kB * kO) + g] = s;
  }
}

extern "C" void kernel_launch(void* const* d_in, const int* in_sizes, int n_in,
                              void* d_out, int out_size, void* d_ws,
                              size_t ws_size, hipStream_t stream) {
  (void)in_sizes;
  (void)n_in;
  (void)out_size;
  (void)ws_size;
  const float* x = (const float*)d_in[0];    // [B,T,784]
  const float* W1 = (const float*)d_in[1];   // [128,784]
  const float* b1 = (const float*)d_in[2];   // [128]
  const float* W2 = (const float*)d_in[3];   // [128,128]
  const float* b2 = (const float*)d_in[4];   // [128]
  const float* W3 = (const float*)d_in[5];   // [10,128]
  const float* b3 = (const float*)d_in[6];   // [10]
  float* out = (float*)d_out;                // [T,B,10]

  float* buf0 = (float*)d_ws;                       // cur1 -> s1 ; later cur3
  float* buf1 = buf0 + (size_t)kM * kH;             // cur2 -> s2
  float* cur3 = buf0;                               // s1 dead after gemm2

  // Layer 1: x is [B,T,784] and row index r = b*T+t matches [B*T,784].
  gemm_nt128<kI><<<kM / 128, 256, 0, stream>>>(x, W1, b1, buf0);
  lif_scan<<<(kB * kH) / 256, 256, 0, stream>>>(buf0);
  // Layer 2
  gemm_nt128<kH><<<kM / 128, 256, 0, stream>>>(buf0, W2, b2, buf1);
  lif_scan<<<(kB * kH) / 256, 256, 0, stream>>>(buf1);
  // Layer 3
  gemm3_n10<<<kM / 64, 320, 0, stream>>>(buf1, W3, b3, cur3);
  lif_scan_out<<<(kB * kO + 255) / 256, 256, 0, stream>>>(cur3, out);
}

// Round 6
// 723.661 us; speedup vs baseline: 4.2302x; 4.2302x over previous
//
#include <hip/hip_runtime.h>

namespace {
constexpr int kB = 512;
constexpr int kT = 200;
constexpr int kI = 784;
constexpr int kH = 128;
constexpr int kO = 10;
constexpr int kM = kB * kT;  // 102400 rows
constexpr float kBeta = 0.9f;
constexpr float kThr = 1.0f;
}  // namespace

// ---------------------------------------------------------------------------
// Helpers for gemm_nt128. Distinct __shared__ arrays are passed by reference
// so after inlining the compiler sees statically distinct LDS objects
// (rounds 2-5 lesson: runtime-indexed As[cur] / lambdas / global_load_lds
// variants all triggered 128-VGPR + multi-GB scratch pathology; round-1's
// exact shape at 68 VGPR is the only clean allocation).
// ---------------------------------------------------------------------------
__device__ __forceinline__ void compute_step(const float (&As)[16][132],
                                             const float (&Bs)[16][132],
                                             int ty4, int tx4,
                                             float (&acc)[8][8]) {
#pragma unroll
  for (int kk = 0; kk < 16; ++kk) {
    float a[8], b[8];
    *reinterpret_cast<float4*>(&a[0]) =
        *reinterpret_cast<const float4*>(&As[kk][ty4]);
    *reinterpret_cast<float4*>(&a[4]) =
        *reinterpret_cast<const float4*>(&As[kk][64 + ty4]);
    *reinterpret_cast<float4*>(&b[0]) =
        *reinterpret_cast<const float4*>(&Bs[kk][tx4]);
    *reinterpret_cast<float4*>(&b[4]) =
        *reinterpret_cast<const float4*>(&Bs[kk][64 + tx4]);
#pragma unroll
    for (int i = 0; i < 8; ++i)
#pragma unroll
      for (int j = 0; j < 8; ++j) acc[i][j] = fmaf(a[i], b[j], acc[i][j]);
  }
}

__device__ __forceinline__ void stage_step(float (&As)[16][132],
                                           float (&Bs)[16][132],
                                           const float* aptr0,
                                           const float* aptr1,
                                           const float* bptr0,
                                           const float* bptr1, int srow0,
                                           int srow1, int sc4, int k0) {
  const float4 va0 = *reinterpret_cast<const float4*>(aptr0 + k0);
  const float4 va1 = *reinterpret_cast<const float4*>(aptr1 + k0);
  const float4 vb0 = *reinterpret_cast<const float4*>(bptr0 + k0);
  const float4 vb1 = *reinterpret_cast<const float4*>(bptr1 + k0);
  As[sc4 + 0][srow0] = va0.x; As[sc4 + 1][srow0] = va0.y;
  As[sc4 + 2][srow0] = va0.z; As[sc4 + 3][srow0] = va0.w;
  As[sc4 + 0][srow1] = va1.x; As[sc4 + 1][srow1] = va1.y;
  As[sc4 + 2][srow1] = va1.z; As[sc4 + 3][srow1] = va1.w;
  Bs[sc4 + 0][srow0] = vb0.x; Bs[sc4 + 1][srow0] = vb0.y;
  Bs[sc4 + 2][srow0] = vb0.z; Bs[sc4 + 3][srow0] = vb0.w;
  Bs[sc4 + 0][srow1] = vb1.x; Bs[sc4 + 1][srow1] = vb1.y;
  Bs[sc4 + 2][srow1] = vb1.z; Bs[sc4 + 3][srow1] = vb1.w;
}

// ---------------------------------------------------------------------------
// C[M][128] = A[M][K] . B[128][K]^T + bias.   K%16==0, M%128==0.
// 128x128 tile, BK=16, 256 threads, 8x8 per-thread register tile.
// Round-1 code shape (proven 68-VGPR clean) + STATIC double buffer:
// 2x-unrolled K loop with compile-time buffer identity, ONE barrier per
// step. STAGE(s+1) sits in the same barrier-free region as COMPUTE(s), so
// the compiler may hoist the global loads into the FMA stream (r1 had them
// pinned between two barriers -> exposed latency, VALUBusy 49%).
// ---------------------------------------------------------------------------
template <int K>
__global__ __launch_bounds__(256, 2) void gemm_nt128(
    const float* __restrict__ A, const float* __restrict__ B,
    const float* __restrict__ bias, float* __restrict__ C) {
  constexpr int BM = 128, BK = 16;
  constexpr int NSTEP = K / BK;
  __shared__ float As0[16][132];
  __shared__ float Bs0[16][132];
  __shared__ float As1[16][132];
  __shared__ float Bs1[16][132];
  const int tid = threadIdx.x;
  const int tx4 = (tid & 15) * 4;
  const int ty4 = (tid >> 4) * 4;
  const int row0 = blockIdx.x * BM;

  const int srow0 = tid >> 2;      // 0..63
  const int srow1 = srow0 + 64;    // 64..127
  const int sc4 = (tid & 3) * 4;   // 0,4,8,12

  const float* aptr0 = A + (size_t)(row0 + srow0) * K + sc4;
  const float* aptr1 = A + (size_t)(row0 + srow1) * K + sc4;
  const float* bptr0 = B + (size_t)srow0 * K + sc4;
  const float* bptr1 = B + (size_t)srow1 * K + sc4;

  float acc[8][8];
#pragma unroll
  for (int i = 0; i < 8; ++i)
#pragma unroll
    for (int j = 0; j < 8; ++j) acc[i][j] = 0.0f;

  stage_step(As0, Bs0, aptr0, aptr1, bptr0, bptr1, srow0, srow1, sc4, 0);
  __syncthreads();

  for (int s = 0; s < NSTEP; s += 2) {
    // even step: consume buf0, stage s+1 into buf1
    compute_step(As0, Bs0, ty4, tx4, acc);
    if (s + 1 < NSTEP)
      stage_step(As1, Bs1, aptr0, aptr1, bptr0, bptr1, srow0, srow1, sc4,
                 (s + 1) * BK);
    __syncthreads();
    if (s + 1 < NSTEP) {
      // odd step: consume buf1, stage s+2 into buf0
      compute_step(As1, Bs1, ty4, tx4, acc);
      if (s + 2 < NSTEP)
        stage_step(As0, Bs0, aptr0, aptr1, bptr0, bptr1, srow0, srow1, sc4,
                   (s + 2) * BK);
      __syncthreads();
    }
  }

#pragma unroll
  for (int i = 0; i < 8; ++i) {
    const int m = (i < 4) ? (ty4 + i) : (64 + ty4 + (i - 4));
    const size_t r = (size_t)(row0 + m);
#pragma unroll
    for (int jh = 0; jh < 2; ++jh) {
      const int n = jh * 64 + tx4;
      float4 v;
      v.x = acc[i][jh * 4 + 0] + bias[n + 0];
      v.y = acc[i][jh * 4 + 1] + bias[n + 1];
      v.z = acc[i][jh * 4 + 2] + bias[n + 2];
      v.w = acc[i][jh * 4 + 3] + bias[n + 3];
      *reinterpret_cast<float4*>(&C[r * 128 + n]) = v;
    }
  }
}

// ---------------------------------------------------------------------------
// In-place LIF scan over time for a [B,T,128] current buffer.
// thread = (b,h). m_new = (beta*m + cur) - s_prev ; s = (m_new > thr).
// Explicit _rn intrinsics forbid FMA contraction so the recurrence matches
// numpy's op-by-op rounding exactly.
// ---------------------------------------------------------------------------
__global__ __launch_bounds__(256) void lif_scan(float* __restrict__ buf) {
  const int g = blockIdx.x * 256 + threadIdx.x;  // 0..65535
  const int b = g >> 7;
  const int h = g & 127;
  const size_t base = (size_t)b * kT * 128 + h;
  float m = 0.0f, s = 0.0f;
#pragma unroll 4
  for (int t = 0; t < kT; ++t) {
    const float cur = buf[base + (size_t)t * 128];
    m = __fsub_rn(__fadd_rn(__fmul_rn(kBeta, m), cur), s);
    s = (m > kThr) ? 1.0f : 0.0f;
    buf[base + (size_t)t * 128] = s;
  }
}

// ---------------------------------------------------------------------------
// GEMM3: cur3[M][10] = s2[M][128] . W3[10][128]^T + b3. 64 rows / block,
// 320 threads, A-tile + W3 staged in LDS, 2 outputs per thread.
// ---------------------------------------------------------------------------
__global__ __launch_bounds__(320) void gemm3_n10(
    const float* __restrict__ A, const float* __restrict__ W3,
    const float* __restrict__ b3, float* __restrict__ C) {
  __shared__ float Ss[64][132];
  __shared__ float Ws[10][132];
  __shared__ float bs[10];
  const int tid = threadIdx.x;
  const size_t row0 = (size_t)blockIdx.x * 64;

  {  // stage W3: 10*128 floats = 320 float4, exactly one per thread
    const int r = tid >> 5;
    const int c4 = (tid & 31) * 4;
    const float4 v = *reinterpret_cast<const float4*>(&W3[r * 128 + c4]);
    Ws[r][c4 + 0] = v.x;
    Ws[r][c4 + 1] = v.y;
    Ws[r][c4 + 2] = v.z;
    Ws[r][c4 + 3] = v.w;
    if (tid < 10) bs[tid] = b3[tid];
  }
  for (int fi = tid; fi < 2048; fi += 320) {  // 64 rows * 32 float4
    const int r = fi >> 5;
    const int c4 = (fi & 31) * 4;
    const float4 v =
        *reinterpret_cast<const float4*>(&A[(row0 + r) * 128 + c4]);
    Ss[r][c4 + 0] = v.x;
    Ss[r][c4 + 1] = v.y;
    Ss[r][c4 + 2] = v.z;
    Ss[r][c4 + 3] = v.w;
  }
  __syncthreads();

#pragma unroll
  for (int l = 0; l < 2; ++l) {
    const int idx = tid + l * 320;  // 0..639
    const int r = idx / 10;
    const int o = idx - r * 10;
    float acc = bs[o];
#pragma unroll
    for (int k = 0; k < 128; k += 4) {
      const float4 a = *reinterpret_cast<const float4*>(&Ss[r][k]);
      const float4 w = *reinterpret_cast<const float4*>(&Ws[o][k]);
      acc = fmaf(a.x, w.x, acc);
      acc = fmaf(a.y, w.y, acc);
      acc = fmaf(a.z, w.z, acc);
      acc = fmaf(a.w, w.w, acc);
    }
    C[(row0 + r) * 10 + o] = acc;
  }
}

// ---------------------------------------------------------------------------
// Output LIF scan: thread = (b,o), reads cur3[(b*T+t)*10+o],
// writes spikes to out[t*B*10 + b*10 + o]  (layout [T,B,O]).
// ---------------------------------------------------------------------------
__global__ __launch_bounds__(256) void lif_scan_out(
    const float* __restrict__ cur3, float* __restrict__ out) {
  const int g = blockIdx.x * 256 + threadIdx.x;  // 0..5119
  if (g >= kB * kO) return;
  const int b = g / kO;
  const int o = g - b * kO;
  float m = 0.0f, s = 0.0f;
#pragma unroll 4
  for (int t = 0; t < kT; ++t) {
    const float c = cur3[((size_t)b * kT + t) * kO + o];
    m = __fsub_rn(__fadd_rn(__fmul_rn(kBeta, m), c), s);
    s = (m > kThr) ? 1.0f : 0.0f;
    out[(size_t)t * (kB * kO) + g] = s;
  }
}

extern "C" void kernel_launch(void* const* d_in, const int* in_sizes, int n_in,
                              void* d_out, int out_size, void* d_ws,
                              size_t ws_size, hipStream_t stream) {
  (void)in_sizes;
  (void)n_in;
  (void)out_size;
  (void)ws_size;
  const float* x = (const float*)d_in[0];    // [B,T,784]
  const float* W1 = (const float*)d_in[1];   // [128,784]
  const float* b1 = (const float*)d_in[2];   // [128]
  const float* W2 = (const float*)d_in[3];   // [128,128]
  const float* b2 = (const float*)d_in[4];   // [128]
  const float* W3 = (const float*)d_in[5];   // [10,128]
  const float* b3 = (const float*)d_in[6];   // [10]
  float* out = (float*)d_out;                // [T,B,10]

  float* buf0 = (float*)d_ws;                       // cur1 -> s1 ; later cur3
  float* buf1 = buf0 + (size_t)kM * kH;             // cur2 -> s2
  float* cur3 = buf0;                               // s1 dead after gemm2

  // Layer 1: x is [B,T,784] and row index r = b*T+t matches [B*T,784].
  gemm_nt128<kI><<<kM / 128, 256, 0, stream>>>(x, W1, b1, buf0);
  lif_scan<<<(kB * kH) / 256, 256, 0, stream>>>(buf0);
  // Layer 2
  gemm_nt128<kH><<<kM / 128, 256, 0, stream>>>(buf0, W2, b2, buf1);
  lif_scan<<<(kB * kH) / 256, 256, 0, stream>>>(buf1);
  // Layer 3
  gemm3_n10<<<kM / 64, 320, 0, stream>>>(buf1, W3, b3, cur3);
  lif_scan_out<<<(kB * kO + 255) / 256, 256, 0, stream>>>(cur3, out);
}

// Round 7
// 418.019 us; speedup vs baseline: 7.3232x; 1.7312x over previous
//
#include <hip/hip_runtime.h>

namespace {
constexpr int kB = 512;
constexpr int kT = 200;
constexpr int kI = 784;
constexpr int kH = 128;
constexpr int kO = 10;
constexpr int kM = kB * kT;  // 102400 rows
constexpr float kBeta = 0.9f;
constexpr float kThr = 1.0f;
constexpr int kSplitK0 = 400;  // 784 = 400 + 384, both % 16 == 0
}  // namespace

// ---------------------------------------------------------------------------
// C[M][128] = A[M][KSTRIDE(cols kbeg..)] . B[128][..]^T (+ bias).
// Round-1's proven 68-VGPR code shape (two barriers/step, scalar transposed
// LDS stores, 8x8 register tile) — UNCHANGED except tile/kbeg decode.
// SPLIT=1: grid = 2*tiles; half = bid&1 computes k-range [0,400) or
// [400,784) and writes raw partial sums to C (+coff for half 1); bias==null.
// SPLIT=0: round-1 behavior exactly (full K, bias added).
// Rationale: occupancy was GRID-limited (800 blocks = 3.1/CU -> 12.5
// waves/CU cap, VALUBusy 49%). Split-K doubles blocks -> ~25 waves/CU;
// latency hiding via TLP, which is what this shape responds to.
// ---------------------------------------------------------------------------
template <int KSTRIDE, int SPLIT>
__global__ __launch_bounds__(256, 2) void gemm_part(
    const float* __restrict__ A, const float* __restrict__ B,
    const float* __restrict__ bias, float* __restrict__ C, size_t coff) {
  constexpr int BM = 128, BK = 16;
  __shared__ float As[BK][BM + 4];
  __shared__ float Bs[BK][BM + 4];
  const int tid = threadIdx.x;
  const int tx = tid & 15;   // n-dim
  const int ty = tid >> 4;   // m-dim
  int tile, kbeg, nsteps;
  if (SPLIT) {
    tile = blockIdx.x >> 1;          // consecutive halves share A rows (L2)
    const int half = blockIdx.x & 1;
    kbeg = half ? kSplitK0 : 0;
    nsteps = half ? (KSTRIDE - kSplitK0) / BK : kSplitK0 / BK;
    if (half) C += coff;
  } else {
    tile = blockIdx.x;
    kbeg = 0;
    nsteps = KSTRIDE / BK;
  }
  const int row0 = tile * BM;

  const int srow0 = tid >> 2;      // 0..63
  const int srow1 = srow0 + 64;    // 64..127
  const int sc4 = (tid & 3) * 4;   // 0,4,8,12

  const float* aptr0 = A + (size_t)(row0 + srow0) * KSTRIDE + kbeg + sc4;
  const float* aptr1 = A + (size_t)(row0 + srow1) * KSTRIDE + kbeg + sc4;
  const float* bptr0 = B + (size_t)srow0 * KSTRIDE + kbeg + sc4;
  const float* bptr1 = B + (size_t)srow1 * KSTRIDE + kbeg + sc4;

  float acc[8][8];
#pragma unroll
  for (int i = 0; i < 8; ++i)
#pragma unroll
    for (int j = 0; j < 8; ++j) acc[i][j] = 0.0f;

  for (int s = 0; s < nsteps; ++s) {
    const int k0 = s * BK;
    __syncthreads();
    {
      const float4 va0 = *reinterpret_cast<const float4*>(aptr0 + k0);
      const float4 va1 = *reinterpret_cast<const float4*>(aptr1 + k0);
      const float4 vb0 = *reinterpret_cast<const float4*>(bptr0 + k0);
      const float4 vb1 = *reinterpret_cast<const float4*>(bptr1 + k0);
      As[sc4 + 0][srow0] = va0.x; As[sc4 + 1][srow0] = va0.y;
      As[sc4 + 2][srow0] = va0.z; As[sc4 + 3][srow0] = va0.w;
      As[sc4 + 0][srow1] = va1.x; As[sc4 + 1][srow1] = va1.y;
      As[sc4 + 2][srow1] = va1.z; As[sc4 + 3][srow1] = va1.w;
      Bs[sc4 + 0][srow0] = vb0.x; Bs[sc4 + 1][srow0] = vb0.y;
      Bs[sc4 + 2][srow0] = vb0.z; Bs[sc4 + 3][srow0] = vb0.w;
      Bs[sc4 + 0][srow1] = vb1.x; Bs[sc4 + 1][srow1] = vb1.y;
      Bs[sc4 + 2][srow1] = vb1.z; Bs[sc4 + 3][srow1] = vb1.w;
    }
    __syncthreads();
#pragma unroll
    for (int kk = 0; kk < BK; ++kk) {
      float a[8], b[8];
      *reinterpret_cast<float4*>(&a[0]) =
          *reinterpret_cast<const float4*>(&As[kk][ty * 4]);
      *reinterpret_cast<float4*>(&a[4]) =
          *reinterpret_cast<const float4*>(&As[kk][64 + ty * 4]);
      *reinterpret_cast<float4*>(&b[0]) =
          *reinterpret_cast<const float4*>(&Bs[kk][tx * 4]);
      *reinterpret_cast<float4*>(&b[4]) =
          *reinterpret_cast<const float4*>(&Bs[kk][64 + tx * 4]);
#pragma unroll
      for (int i = 0; i < 8; ++i)
#pragma unroll
        for (int j = 0; j < 8; ++j) acc[i][j] = fmaf(a[i], b[j], acc[i][j]);
    }
  }

#pragma unroll
  for (int i = 0; i < 8; ++i) {
    const int m = (i < 4) ? (ty * 4 + i) : (64 + ty * 4 + (i - 4));
    const size_t r = (size_t)(row0 + m);
#pragma unroll
    for (int jh = 0; jh < 2; ++jh) {
      const int n = jh * 64 + tx * 4;
      float4 v;
      v.x = acc[i][jh * 4 + 0];
      v.y = acc[i][jh * 4 + 1];
      v.z = acc[i][jh * 4 + 2];
      v.w = acc[i][jh * 4 + 3];
      if (bias != nullptr) {
        v.x += bias[n + 0];
        v.y += bias[n + 1];
        v.z += bias[n + 2];
        v.w += bias[n + 3];
      }
      *reinterpret_cast<float4*>(&C[r * 128 + n]) = v;
    }
  }
}

// ---------------------------------------------------------------------------
// Layer-1 LIF scan, fused partial-sum combine: cur = (P0 + P1) + b1.
// Thread = (b, h4): scans 4 neurons via float4. Writes spikes into P0.
// Per-element op order via _rn intrinsics matches numpy's rounding exactly
// (modulo the split-K reorder of the dot product, same class as GEMM tiling).
// ---------------------------------------------------------------------------
__global__ __launch_bounds__(256) void lif_scan13(
    float* __restrict__ P0, const float* __restrict__ P1,
    const float* __restrict__ b1) {
  const int g = blockIdx.x * 256 + threadIdx.x;  // 0..16383
  const int b = g >> 5;
  const int h4 = (g & 31) * 4;
  const size_t base = (size_t)b * kT * 128 + h4;
  const float4 bb = *reinterpret_cast<const float4*>(&b1[h4]);
  float4 m = {0.f, 0.f, 0.f, 0.f}, s = {0.f, 0.f, 0.f, 0.f};
  for (int t = 0; t < kT; ++t) {
    const size_t idx = base + (size_t)t * 128;
    const float4 c0 = *reinterpret_cast<const float4*>(&P0[idx]);
    const float4 c1 = *reinterpret_cast<const float4*>(&P1[idx]);
    float4 sp;
#define LIF1(c)                                                        \
  {                                                                    \
    const float cur = __fadd_rn(__fadd_rn(c0.c, c1.c), bb.c);          \
    m.c = __fsub_rn(__fadd_rn(__fmul_rn(kBeta, m.c), cur), s.c);       \
    sp.c = (m.c > kThr) ? 1.0f : 0.0f;                                 \
  }
    LIF1(x) LIF1(y) LIF1(z) LIF1(w)
#undef LIF1
    s = sp;
    *reinterpret_cast<float4*>(&P0[idx]) = sp;
  }
}

// ---------------------------------------------------------------------------
// Layer-2 LIF scan, in place on cur2 (bias already applied by GEMM2).
// ---------------------------------------------------------------------------
__global__ __launch_bounds__(256) void lif_scan2(float* __restrict__ buf) {
  const int g = blockIdx.x * 256 + threadIdx.x;  // 0..16383
  const int b = g >> 5;
  const int h4 = (g & 31) * 4;
  const size_t base = (size_t)b * kT * 128 + h4;
  float4 m = {0.f, 0.f, 0.f, 0.f}, s = {0.f, 0.f, 0.f, 0.f};
  for (int t = 0; t < kT; ++t) {
    const size_t idx = base + (size_t)t * 128;
    const float4 c0 = *reinterpret_cast<const float4*>(&buf[idx]);
    float4 sp;
#define LIF1(c)                                                        \
  {                                                                    \
    m.c = __fsub_rn(__fadd_rn(__fmul_rn(kBeta, m.c), c0.c), s.c);      \
    sp.c = (m.c > kThr) ? 1.0f : 0.0f;                                 \
  }
    LIF1(x) LIF1(y) LIF1(z) LIF1(w)
#undef LIF1
    s = sp;
    *reinterpret_cast<float4*>(&buf[idx]) = sp;
  }
}

// ---------------------------------------------------------------------------
// GEMM3: cur3[M][10] = s2[M][128] . W3[10][128]^T + b3. 64 rows / block,
// 320 threads, A-tile + W3 staged in LDS, 2 outputs per thread.
// ---------------------------------------------------------------------------
__global__ __launch_bounds__(320) void gemm3_n10(
    const float* __restrict__ A, const float* __restrict__ W3,
    const float* __restrict__ b3, float* __restrict__ C) {
  __shared__ float Ss[64][132];
  __shared__ float Ws[10][132];
  __shared__ float bs[10];
  const int tid = threadIdx.x;
  const size_t row0 = (size_t)blockIdx.x * 64;

  {  // stage W3: 10*128 floats = 320 float4, exactly one per thread
    const int r = tid >> 5;
    const int c4 = (tid & 31) * 4;
    const float4 v = *reinterpret_cast<const float4*>(&W3[r * 128 + c4]);
    Ws[r][c4 + 0] = v.x;
    Ws[r][c4 + 1] = v.y;
    Ws[r][c4 + 2] = v.z;
    Ws[r][c4 + 3] = v.w;
    if (tid < 10) bs[tid] = b3[tid];
  }
  for (int fi = tid; fi < 2048; fi += 320) {  // 64 rows * 32 float4
    const int r = fi >> 5;
    const int c4 = (fi & 31) * 4;
    const float4 v =
        *reinterpret_cast<const float4*>(&A[(row0 + r) * 128 + c4]);
    Ss[r][c4 + 0] = v.x;
    Ss[r][c4 + 1] = v.y;
    Ss[r][c4 + 2] = v.z;
    Ss[r][c4 + 3] = v.w;
  }
  __syncthreads();

#pragma unroll
  for (int l = 0; l < 2; ++l) {
    const int idx = tid + l * 320;  // 0..639
    const int r = idx / 10;
    const int o = idx - r * 10;
    float acc = bs[o];
#pragma unroll
    for (int k = 0; k < 128; k += 4) {
      const float4 a = *reinterpret_cast<const float4*>(&Ss[r][k]);
      const float4 w = *reinterpret_cast<const float4*>(&Ws[o][k]);
      acc = fmaf(a.x, w.x, acc);
      acc = fmaf(a.y, w.y, acc);
      acc = fmaf(a.z, w.z, acc);
      acc = fmaf(a.w, w.w, acc);
    }
    C[(row0 + r) * 10 + o] = acc;
  }
}

// ---------------------------------------------------------------------------
// Output LIF scan: thread = (b,o), reads cur3[(b*T+t)*10+o],
// writes spikes to out[t*B*10 + b*10 + o]  (layout [T,B,O]).
// ---------------------------------------------------------------------------
__global__ __launch_bounds__(256) void lif_scan_out(
    const float* __restrict__ cur3, float* __restrict__ out) {
  const int g = blockIdx.x * 256 + threadIdx.x;  // 0..5119
  if (g >= kB * kO) return;
  const int b = g / kO;
  const int o = g - b * kO;
  float m = 0.0f, s = 0.0f;
#pragma unroll 4
  for (int t = 0; t < kT; ++t) {
    const float c = cur3[((size_t)b * kT + t) * kO + o];
    m = __fsub_rn(__fadd_rn(__fmul_rn(kBeta, m), c), s);
    s = (m > kThr) ? 1.0f : 0.0f;
    out[(size_t)t * (kB * kO) + g] = s;
  }
}

extern "C" void kernel_launch(void* const* d_in, const int* in_sizes, int n_in,
                              void* d_out, int out_size, void* d_ws,
                              size_t ws_size, hipStream_t stream) {
  (void)in_sizes;
  (void)n_in;
  (void)out_size;
  (void)ws_size;
  const float* x = (const float*)d_in[0];    // [B,T,784]
  const float* W1 = (const float*)d_in[1];   // [128,784]
  const float* b1 = (const float*)d_in[2];   // [128]
  const float* W2 = (const float*)d_in[3];   // [128,128]
  const float* b2 = (const float*)d_in[4];   // [128]
  const float* W3 = (const float*)d_in[5];   // [10,128]
  const float* b3 = (const float*)d_in[6];   // [10]
  float* out = (float*)d_out;                // [T,B,10]

  const size_t bufElems = (size_t)kM * kH;   // 13.1M floats = 52.4 MB
  float* P0 = (float*)d_ws;                  // partial0 -> s1 -> cur3
  float* P1 = P0 + bufElems;                 // partial1 (dies) -> cur2 -> s2

  // Layer 1: split-K GEMM (halves [0,400) and [400,784)), one 1600-block
  // dispatch; scan combines P0+P1+b1 and writes s1 into P0.
  gemm_part<kI, 1><<<2 * (kM / 128), 256, 0, stream>>>(
      x, W1, nullptr, P0, bufElems);
  lif_scan13<<<(kB * kH / 4) / 256, 256, 0, stream>>>(P0, P1, b1);
  // Layer 2: full-K GEMM (round-1 behavior), cur2 -> P1 region.
  gemm_part<kH, 0><<<kM / 128, 256, 0, stream>>>(P0, W2, b2, P1, 0);
  lif_scan2<<<(kB * kH / 4) / 256, 256, 0, stream>>>(P1);
  // Layer 3: cur3 -> P0 region (s1 dead).
  gemm3_n10<<<kM / 64, 320, 0, stream>>>(P1, W3, b3, P0);
  lif_scan_out<<<(kB * kO + 255) / 256, 256, 0, stream>>>(P0, out);
}

// Round 8
// 403.414 us; speedup vs baseline: 7.5884x; 1.0362x over previous
//
#include <hip/hip_runtime.h>

namespace {
constexpr int kB = 512;
constexpr int kT = 200;
constexpr int kI = 784;
constexpr int kH = 128;
constexpr int kO = 10;
constexpr int kM = kB * kT;  // 102400 rows
constexpr float kBeta = 0.9f;
constexpr float kThr = 1.0f;
constexpr int kSplitK0 = 400;  // 784 = 400 + 384, both % 16 == 0
}  // namespace

// ---------------------------------------------------------------------------
// C[M][128] = A[M][K-slice] . B[128][K-slice]^T (+ bias).
// BM=64 x BN=128 tile, 128 threads (2 waves), 8x8 per-thread register tile
// (same FMA:LDS-dword ratio and same per-output k-order as the proven
// round-1/7 shape — only the block granularity changes).
// Rationale: occupancy was the limiter (27% realized vs 4-blocks/CU VGPR
// cap). 128-thread blocks double the grid: GEMM1 = 3200 blocks x 2 waves
// (~25 waves/CU queued vs 16-wave cap) -> latency hiding via TLP.
// SPLIT=1: halves [0,400)/[400,784) write raw partials (bias=null).
// ---------------------------------------------------------------------------
template <int KSTRIDE, int SPLIT>
__global__ __launch_bounds__(128, 4) void gemm64(
    const float* __restrict__ A, const float* __restrict__ B,
    const float* __restrict__ bias, float* __restrict__ C, size_t coff) {
  constexpr int BM = 64, BK = 16;
  __shared__ float As[BK][BM + 4];
  __shared__ float Bs[BK][128 + 4];
  const int tid = threadIdx.x;
  const int tx = tid & 15;   // n-dim 0..15
  const int ty = tid >> 4;   // m-dim 0..7
  int tile, kbeg, nsteps;
  if (SPLIT) {
    tile = blockIdx.x >> 1;          // halves adjacent: share C rows
    const int half = blockIdx.x & 1;
    kbeg = half ? kSplitK0 : 0;
    nsteps = half ? (KSTRIDE - kSplitK0) / BK : kSplitK0 / BK;
    if (half) C += coff;
  } else {
    tile = blockIdx.x;
    kbeg = 0;
    nsteps = KSTRIDE / BK;
  }
  const int row0 = tile * BM;

  // A staging: 64 rows x 4 float4 = 256 float4 / 128 thr = 2 each.
  const int ar0 = tid >> 2;            // 0..31
  const int ar1 = ar0 + 32;            // 32..63
  const int ac4 = (tid & 3) * 4;
  // B staging: 128 rows x 4 float4 = 512 float4 / 128 thr = 4 each.
  const int br0 = tid >> 2;            // 0..31 (+32 per l)
  const int bc4 = (tid & 3) * 4;

  const float* aptr0 = A + (size_t)(row0 + ar0) * KSTRIDE + kbeg + ac4;
  const float* aptr1 = A + (size_t)(row0 + ar1) * KSTRIDE + kbeg + ac4;
  const float* bptr = B + (size_t)br0 * KSTRIDE + kbeg + bc4;

  float acc[8][8];
#pragma unroll
  for (int i = 0; i < 8; ++i)
#pragma unroll
    for (int j = 0; j < 8; ++j) acc[i][j] = 0.0f;

  for (int s = 0; s < nsteps; ++s) {
    const int k0 = s * BK;
    __syncthreads();
    {
      const float4 va0 = *reinterpret_cast<const float4*>(aptr0 + k0);
      const float4 va1 = *reinterpret_cast<const float4*>(aptr1 + k0);
      As[ac4 + 0][ar0] = va0.x; As[ac4 + 1][ar0] = va0.y;
      As[ac4 + 2][ar0] = va0.z; As[ac4 + 3][ar0] = va0.w;
      As[ac4 + 0][ar1] = va1.x; As[ac4 + 1][ar1] = va1.y;
      As[ac4 + 2][ar1] = va1.z; As[ac4 + 3][ar1] = va1.w;
#pragma unroll
      for (int l = 0; l < 4; ++l) {
        const float4 vb = *reinterpret_cast<const float4*>(
            bptr + (size_t)l * 32 * KSTRIDE + k0);
        const int r = br0 + l * 32;
        Bs[bc4 + 0][r] = vb.x; Bs[bc4 + 1][r] = vb.y;
        Bs[bc4 + 2][r] = vb.z; Bs[bc4 + 3][r] = vb.w;
      }
    }
    __syncthreads();
#pragma unroll
    for (int kk = 0; kk < BK; ++kk) {
      float a[8], b[8];
      *reinterpret_cast<float4*>(&a[0]) =
          *reinterpret_cast<const float4*>(&As[kk][ty * 4]);
      *reinterpret_cast<float4*>(&a[4]) =
          *reinterpret_cast<const float4*>(&As[kk][32 + ty * 4]);
      *reinterpret_cast<float4*>(&b[0]) =
          *reinterpret_cast<const float4*>(&Bs[kk][tx * 4]);
      *reinterpret_cast<float4*>(&b[4]) =
          *reinterpret_cast<const float4*>(&Bs[kk][64 + tx * 4]);
#pragma unroll
      for (int i = 0; i < 8; ++i)
#pragma unroll
        for (int j = 0; j < 8; ++j) acc[i][j] = fmaf(a[i], b[j], acc[i][j]);
    }
  }

#pragma unroll
  for (int i = 0; i < 8; ++i) {
    const int m = (i < 4) ? (ty * 4 + i) : (32 + ty * 4 + (i - 4));
    const size_t r = (size_t)(row0 + m);
#pragma unroll
    for (int jh = 0; jh < 2; ++jh) {
      const int n = jh * 64 + tx * 4;
      float4 v;
      v.x = acc[i][jh * 4 + 0];
      v.y = acc[i][jh * 4 + 1];
      v.z = acc[i][jh * 4 + 2];
      v.w = acc[i][jh * 4 + 3];
      if (bias != nullptr) {
        v.x += bias[n + 0];
        v.y += bias[n + 1];
        v.z += bias[n + 2];
        v.w += bias[n + 3];
      }
      *reinterpret_cast<float4*>(&C[r * 128 + n]) = v;
    }
  }
}

// ---------------------------------------------------------------------------
// Layer-1 LIF scan + partial combine: cur = (P0+P1) + b1; spikes -> P0.
// Scalar thread-per-(b,h): 256 blocks (r7's float4 version ran on only 64
// blocks — under-parallelized). _rn op order matches numpy exactly and the
// (c0+c1)+b combine order is the round-7-proven one.
// ---------------------------------------------------------------------------
__global__ __launch_bounds__(256) void lif_scan13(
    float* __restrict__ P0, const float* __restrict__ P1,
    const float* __restrict__ b1) {
  const int g = blockIdx.x * 256 + threadIdx.x;  // 0..65535
  const int b = g >> 7;
  const int h = g & 127;
  const size_t base = (size_t)b * kT * 128 + h;
  const float bb = b1[h];
  float m = 0.0f, s = 0.0f;
#pragma unroll 4
  for (int t = 0; t < kT; ++t) {
    const size_t idx = base + (size_t)t * 128;
    const float cur = __fadd_rn(__fadd_rn(P0[idx], P1[idx]), bb);
    m = __fsub_rn(__fadd_rn(__fmul_rn(kBeta, m), cur), s);
    s = (m > kThr) ? 1.0f : 0.0f;
    P0[idx] = s;
  }
}

// ---------------------------------------------------------------------------
// Layer-2 LIF scan, in place (bias already applied by GEMM2).
// ---------------------------------------------------------------------------
__global__ __launch_bounds__(256) void lif_scan2(float* __restrict__ buf) {
  const int g = blockIdx.x * 256 + threadIdx.x;  // 0..65535
  const int b = g >> 7;
  const int h = g & 127;
  const size_t base = (size_t)b * kT * 128 + h;
  float m = 0.0f, s = 0.0f;
#pragma unroll 4
  for (int t = 0; t < kT; ++t) {
    const size_t idx = base + (size_t)t * 128;
    m = __fsub_rn(__fadd_rn(__fmul_rn(kBeta, m), buf[idx]), s);
    s = (m > kThr) ? 1.0f : 0.0f;
    buf[idx] = s;
  }
}

// ---------------------------------------------------------------------------
// GEMM3: cur3[M][10] = s2[M][128] . W3[10][128]^T + b3. 64 rows / block,
// 320 threads, A-tile + W3 staged in LDS, 2 outputs per thread.
// ---------------------------------------------------------------------------
__global__ __launch_bounds__(320) void gemm3_n10(
    const float* __restrict__ A, const float* __restrict__ W3,
    const float* __restrict__ b3, float* __restrict__ C) {
  __shared__ float Ss[64][132];
  __shared__ float Ws[10][132];
  __shared__ float bs[10];
  const int tid = threadIdx.x;
  const size_t row0 = (size_t)blockIdx.x * 64;

  {  // stage W3: 10*128 floats = 320 float4, exactly one per thread
    const int r = tid >> 5;
    const int c4 = (tid & 31) * 4;
    const float4 v = *reinterpret_cast<const float4*>(&W3[r * 128 + c4]);
    Ws[r][c4 + 0] = v.x;
    Ws[r][c4 + 1] = v.y;
    Ws[r][c4 + 2] = v.z;
    Ws[r][c4 + 3] = v.w;
    if (tid < 10) bs[tid] = b3[tid];
  }
  for (int fi = tid; fi < 2048; fi += 320) {  // 64 rows * 32 float4
    const int r = fi >> 5;
    const int c4 = (fi & 31) * 4;
    const float4 v =
        *reinterpret_cast<const float4*>(&A[(row0 + r) * 128 + c4]);
    Ss[r][c4 + 0] = v.x;
    Ss[r][c4 + 1] = v.y;
    Ss[r][c4 + 2] = v.z;
    Ss[r][c4 + 3] = v.w;
  }
  __syncthreads();

#pragma unroll
  for (int l = 0; l < 2; ++l) {
    const int idx = tid + l * 320;  // 0..639
    const int r = idx / 10;
    const int o = idx - r * 10;
    float acc = bs[o];
#pragma unroll
    for (int k = 0; k < 128; k += 4) {
      const float4 a = *reinterpret_cast<const float4*>(&Ss[r][k]);
      const float4 w = *reinterpret_cast<const float4*>(&Ws[o][k]);
      acc = fmaf(a.x, w.x, acc);
      acc = fmaf(a.y, w.y, acc);
      acc = fmaf(a.z, w.z, acc);
      acc = fmaf(a.w, w.w, acc);
    }
    C[(row0 + r) * 10 + o] = acc;
  }
}

// ---------------------------------------------------------------------------
// Output LIF scan: thread = (b,o), reads cur3[(b*T+t)*10+o],
// writes spikes to out[t*B*10 + b*10 + o]  (layout [T,B,O]).
// ---------------------------------------------------------------------------
__global__ __launch_bounds__(256) void lif_scan_out(
    const float* __restrict__ cur3, float* __restrict__ out) {
  const int g = blockIdx.x * 256 + threadIdx.x;  // 0..5119
  if (g >= kB * kO) return;
  const int b = g / kO;
  const int o = g - b * kO;
  float m = 0.0f, s = 0.0f;
#pragma unroll 4
  for (int t = 0; t < kT; ++t) {
    const float c = cur3[((size_t)b * kT + t) * kO + o];
    m = __fsub_rn(__fadd_rn(__fmul_rn(kBeta, m), c), s);
    s = (m > kThr) ? 1.0f : 0.0f;
    out[(size_t)t * (kB * kO) + g] = s;
  }
}

extern "C" void kernel_launch(void* const* d_in, const int* in_sizes, int n_in,
                              void* d_out, int out_size, void* d_ws,
                              size_t ws_size, hipStream_t stream) {
  (void)in_sizes;
  (void)n_in;
  (void)out_size;
  (void)ws_size;
  const float* x = (const float*)d_in[0];    // [B,T,784]
  const float* W1 = (const float*)d_in[1];   // [128,784]
  const float* b1 = (const float*)d_in[2];   // [128]
  const float* W2 = (const float*)d_in[3];   // [128,128]
  const float* b2 = (const float*)d_in[4];   // [128]
  const float* W3 = (const float*)d_in[5];   // [10,128]
  const float* b3 = (const float*)d_in[6];   // [10]
  float* out = (float*)d_out;                // [T,B,10]

  const size_t bufElems = (size_t)kM * kH;   // 13.1M floats = 52.4 MB
  float* P0 = (float*)d_ws;                  // partial0 -> s1 -> cur3
  float* P1 = P0 + bufElems;                 // partial1 -> cur2 -> s2

  // Layer 1: split-K GEMM, 3200 blocks x 128 threads; scan combines.
  gemm64<kI, 1><<<2 * (kM / 64), 128, 0, stream>>>(x, W1, nullptr, P0,
                                                   bufElems);
  lif_scan13<<<(kB * kH) / 256, 256, 0, stream>>>(P0, P1, b1);
  // Layer 2: full-K GEMM, 1600 blocks.
  gemm64<kH, 0><<<kM / 64, 128, 0, stream>>>(P0, W2, b2, P1, 0);
  lif_scan2<<<(kB * kH) / 256, 256, 0, stream>>>(P1);
  // Layer 3: cur3 -> P0 region (s1 dead).
  gemm3_n10<<<kM / 64, 320, 0, stream>>>(P1, W3, b3, P0);
  lif_scan_out<<<(kB * kO + 255) / 256, 256, 0, stream>>>(P0, out);
}